// Round 1
// baseline (549.237 us; speedup 1.0000x reference)
//
#include <hip/hip_runtime.h>
#include <hip/hip_bf16.h>
#include <stdint.h>

#define IN_FEATS 128
#define OUT_FEATS 256
#define TOPK 32
#define BM 128
#define BN 128
#define BK 32
#define AL 40   /* padded LDS row stride (elems): 32 + 8 -> 80B, breaks bank aliasing */
#define KTOT 256

typedef float f32x4 __attribute__((ext_vector_type(4)));
typedef short bf16x8 __attribute__((ext_vector_type(8)));

__device__ __forceinline__ unsigned short f2bf(float x) {
    unsigned u = __float_as_uint(x);
    u += 0x7FFFu + ((u >> 16) & 1u);   // round-to-nearest-even
    return (unsigned short)(u >> 16);
}
__device__ __forceinline__ float bf2f(unsigned short h) {
    return __uint_as_float(((unsigned)h) << 16);
}

// K1: scatter top-k (values,indices) into dense bf16 x_sparse [N,128].
// Duplicate indices must ACCUMULATE (reference uses .add) -> atomicAdd in LDS.
__global__ void k_scatter(const float* __restrict__ vals, const int* __restrict__ idxs,
                          unsigned short* __restrict__ xsp, int n_nodes) {
    __shared__ float lds[2 * IN_FEATS];
    int t = threadIdx.x;
    int n0 = blockIdx.x * 2;
    lds[t] = 0.f;
    __syncthreads();
    if (t < 2 * TOPK) {
        int h = t >> 5;          // which of the 2 nodes
        int k = t & 31;
        int n = n0 + h;
        if (n < n_nodes) {
            float v = vals[(size_t)n * TOPK + k];
            int ix = idxs[(size_t)n * TOPK + k];
            atomicAdd(&lds[h * IN_FEATS + ix], v);
        }
    }
    __syncthreads();
    int h2 = t >> 7;
    int f = t & 127;
    int n = n0 + h2;
    if (n < n_nodes) xsp[(size_t)n * IN_FEATS + f] = f2bf(lds[t]);
}

// Kw: build W^T bf16 [256 outs][256 ks], rows = output col, concat K = [W_neigh; W_self]
__global__ void k_weights(const float* __restrict__ Wn, const float* __restrict__ Ws,
                          unsigned short* __restrict__ WT) {
    int idx = blockIdx.x * 256 + threadIdx.x;   // 0..65535
    int n = idx >> 8;
    int k = idx & 255;
    float v = (k < IN_FEATS) ? Wn[(size_t)k * OUT_FEATS + n]
                             : Ws[(size_t)(k - IN_FEATS) * OUT_FEATS + n];
    WT[idx] = f2bf(v);
}

// K2: mean aggregation. One wave (64 lanes) per node; each lane owns 2 features.
// Edge range for the node via binary search on sorted row[].
__global__ void k_aggregate(const unsigned short* __restrict__ xsp,
                            const int* __restrict__ row, const int* __restrict__ col,
                            const float* __restrict__ deg,
                            unsigned short* __restrict__ agg,
                            int n_nodes, int n_edges) {
    int t = threadIdx.x;
    int node = blockIdx.x * 4 + (t >> 6);
    if (node >= n_nodes) return;
    int lane = t & 63;

    int lo = 0, hi = n_edges;
    while (lo < hi) { int mid = (lo + hi) >> 1; if (row[mid] < node) lo = mid + 1; else hi = mid; }
    int e0 = lo;
    hi = n_edges;
    while (lo < hi) { int mid = (lo + hi) >> 1; if (row[mid] < node + 1) lo = mid + 1; else hi = mid; }
    int e1 = lo;

    float ax = 0.f, ay = 0.f;
    for (int e = e0; e < e1; ++e) {
        int c = col[e];
        unsigned v = *(const unsigned*)(xsp + (size_t)c * IN_FEATS + lane * 2);
        ax += bf2f((unsigned short)(v & 0xFFFFu));
        ay += bf2f((unsigned short)(v >> 16));
    }
    float inv = 1.0f / deg[node];
    ax *= inv; ay *= inv;
    unsigned o = (unsigned)f2bf(ax) | ((unsigned)f2bf(ay) << 16);
    *(unsigned*)(agg + (size_t)node * IN_FEATS + lane * 2) = o;
}

// K3: rst = [agg | feat_bf16] @ Wcat + bias.  M=n_nodes, K=256, N=256.
// 128x128 tile, 4 waves, each wave a 4x4 grid of 16x16x32 bf16 MFMAs.
__global__ __launch_bounds__(256) void k_gemm(
    const unsigned short* __restrict__ agg,   // [N,128] bf16
    const float* __restrict__ feat,           // [N,128] f32 (cast during staging)
    const unsigned short* __restrict__ WT,    // [256][256] bf16, WT[n][k]
    const float* __restrict__ bias,
    float* __restrict__ out, int n_nodes) {
    __shared__ __align__(16) unsigned short Ash[BM * AL];
    __shared__ __align__(16) unsigned short Bsh[BN * AL];
    int t = threadIdx.x;
    int m0 = blockIdx.x * BM;
    int n0 = blockIdx.y * BN;
    int lane = t & 63;
    int w = t >> 6;
    int wr = w >> 1, wc = w & 1;
    int lrow = lane & 15, quad = lane >> 4;

    f32x4 acc[4][4];
    for (int i = 0; i < 4; ++i)
        for (int j = 0; j < 4; ++j)
            acc[i][j] = (f32x4){0.f, 0.f, 0.f, 0.f};

    for (int kk = 0; kk < KTOT; kk += BK) {
        // ---- stage A (128 rows x 32 k, bf16) and B (128 ncols x 32 k) ----
        for (int pass = 0; pass < 2; ++pass) {
            int g = t + pass * 256;          // 0..511 -> (row, 8-elem group)
            int rowi = g >> 2;
            int q = g & 3;
            int gk = kk + q * 8;
            int node = m0 + rowi;
            if (node >= n_nodes) node = n_nodes - 1;  // clamp: keep loads in-bounds
            uint4 v;
            if (kk < IN_FEATS) {
                v = *(const uint4*)(agg + (size_t)node * IN_FEATS + gk);
            } else {
                const float* fp = feat + (size_t)node * IN_FEATS + (gk - IN_FEATS);
                float4 f0 = *(const float4*)fp;
                float4 f1 = *(const float4*)(fp + 4);
                v.x = (unsigned)f2bf(f0.x) | ((unsigned)f2bf(f0.y) << 16);
                v.y = (unsigned)f2bf(f0.z) | ((unsigned)f2bf(f0.w) << 16);
                v.z = (unsigned)f2bf(f1.x) | ((unsigned)f2bf(f1.y) << 16);
                v.w = (unsigned)f2bf(f1.z) | ((unsigned)f2bf(f1.w) << 16);
            }
            *(uint4*)&Ash[rowi * AL + q * 8] = v;

            uint4 bv = *(const uint4*)(WT + (size_t)(n0 + rowi) * KTOT + gk);
            *(uint4*)&Bsh[rowi * AL + q * 8] = bv;
        }
        __syncthreads();

        bf16x8 af[4], bfr[4];
        for (int mi = 0; mi < 4; ++mi)
            af[mi] = *(const bf16x8*)&Ash[(wr * 64 + mi * 16 + lrow) * AL + quad * 8];
        for (int ni = 0; ni < 4; ++ni)
            bfr[ni] = *(const bf16x8*)&Bsh[(wc * 64 + ni * 16 + lrow) * AL + quad * 8];
        for (int mi = 0; mi < 4; ++mi)
            for (int ni = 0; ni < 4; ++ni)
                acc[mi][ni] = __builtin_amdgcn_mfma_f32_16x16x32_bf16(
                    af[mi], bfr[ni], acc[mi][ni], 0, 0, 0);
        __syncthreads();
    }

    // epilogue: C/D layout col=lane&15, row=quad*4+reg
    for (int mi = 0; mi < 4; ++mi) {
        int gm = m0 + wr * 64 + mi * 16 + quad * 4;
        for (int ni = 0; ni < 4; ++ni) {
            int go = n0 + wc * 64 + ni * 16 + lrow;
            float b = bias[go];
            for (int r = 0; r < 4; ++r) {
                int node = gm + r;
                if (node < n_nodes)
                    out[(size_t)node * OUT_FEATS + go] = acc[mi][ni][r] + b;
            }
        }
    }
}

extern "C" void kernel_launch(void* const* d_in, const int* in_sizes, int n_in,
                              void* d_out, int out_size, void* d_ws, size_t ws_size,
                              hipStream_t stream) {
    const float* feat = (const float*)d_in[0];
    const float* tkv  = (const float*)d_in[1];
    const int*   tki  = (const int*)d_in[2];
    const int*   row  = (const int*)d_in[3];
    const int*   col  = (const int*)d_in[4];
    const float* deg  = (const float*)d_in[5];
    const float* Wn   = (const float*)d_in[6];
    const float* Ws   = (const float*)d_in[7];
    const float* bias = (const float*)d_in[8];
    float* out = (float*)d_out;

    int n_nodes = in_sizes[5];
    int n_edges = in_sizes[3];

    // ws layout: x_sparse bf16 [N,128] | agg bf16 [N,128] | WT bf16 [256,256]
    unsigned short* xsp = (unsigned short*)d_ws;
    unsigned short* agg = xsp + (size_t)n_nodes * IN_FEATS;
    unsigned short* WT  = agg + (size_t)n_nodes * IN_FEATS;

    k_scatter<<<(n_nodes + 1) / 2, 256, 0, stream>>>(tkv, tki, xsp, n_nodes);
    k_weights<<<256, 256, 0, stream>>>(Wn, Ws, WT);
    k_aggregate<<<(n_nodes + 3) / 4, 256, 0, stream>>>(xsp, row, col, deg, agg, n_nodes, n_edges);
    dim3 g3((n_nodes + BM - 1) / BM, OUT_FEATS / BN);
    k_gemm<<<g3, 256, 0, stream>>>(agg, feat, WT, bias, out, n_nodes);
}

// Round 3
// 305.427 us; speedup vs baseline: 1.7983x; 1.7983x over previous
//
#include <hip/hip_runtime.h>
#include <hip/hip_bf16.h>
#include <stdint.h>

#define IN_FEATS 128
#define OUT_FEATS 256
#define TOPK 32
#define BM 128
#define BN 128
#define BK 32
#define AL 40   /* padded LDS row stride (elems): 32 + 8 -> 80B, breaks bank aliasing */
#define KTOT 256

typedef float f32x4 __attribute__((ext_vector_type(4)));
typedef short bf16x8 __attribute__((ext_vector_type(8)));

__device__ __forceinline__ unsigned short f2bf(float x) {
    unsigned u = __float_as_uint(x);
    u += 0x7FFFu + ((u >> 16) & 1u);   // round-to-nearest-even
    return (unsigned short)(u >> 16);
}

// K1: scatter top-k (values,indices) into dense bf16 x_sparse [N,128].
// Duplicate indices must ACCUMULATE (reference uses .add) -> atomicAdd in LDS.
__global__ void k_scatter(const float* __restrict__ vals, const int* __restrict__ idxs,
                          unsigned short* __restrict__ xsp, int n_nodes) {
    __shared__ float lds[2 * IN_FEATS];
    int t = threadIdx.x;
    int n0 = blockIdx.x * 2;
    lds[t] = 0.f;
    __syncthreads();
    if (t < 2 * TOPK) {
        int h = t >> 5;          // which of the 2 nodes
        int k = t & 31;
        int n = n0 + h;
        if (n < n_nodes) {
            float v = vals[(size_t)n * TOPK + k];
            int ix = idxs[(size_t)n * TOPK + k];
            atomicAdd(&lds[h * IN_FEATS + ix], v);
        }
    }
    __syncthreads();
    int h2 = t >> 7;
    int f = t & 127;
    int n = n0 + h2;
    if (n < n_nodes) xsp[(size_t)n * IN_FEATS + f] = f2bf(lds[t]);
}

// Kw: build W^T bf16 [256 outs][256 ks], rows = output col, concat K = [W_neigh; W_self]
__global__ void k_weights(const float* __restrict__ Wn, const float* __restrict__ Ws,
                          unsigned short* __restrict__ WT) {
    int idx = blockIdx.x * 256 + threadIdx.x;   // 0..65535
    int n = idx >> 8;
    int k = idx & 255;
    float v = (k < IN_FEATS) ? Wn[(size_t)k * OUT_FEATS + n]
                             : Ws[(size_t)(k - IN_FEATS) * OUT_FEATS + n];
    WT[idx] = f2bf(v);
}

// Ki: build indptr[N+1] from sorted row[] (edge-parallel, writes gap ranges).
__global__ void k_indptr(const int* __restrict__ row, int* __restrict__ indptr,
                         int n_nodes, int n_edges) {
    int e = blockIdx.x * 256 + threadIdx.x;
    if (e >= n_edges) return;
    int r = row[e];
    int rp = (e == 0) ? -1 : row[e - 1];
    for (int x = rp + 1; x <= r; ++x) indptr[x] = e;
    if (e == n_edges - 1)
        for (int x = r + 1; x <= n_nodes; ++x) indptr[x] = n_edges;
}

// K2: mean aggregation. One wave per node. lane = eg*16 + fi:
// 16 lanes x 16B cover one bf16 feature row; 4 edges (eg) per wave-load,
// unrolled x2 -> 8 gathers in flight. Predicated by scale, no divergence.
__global__ __launch_bounds__(256) void k_aggregate(
    const unsigned short* __restrict__ xsp,
    const int* __restrict__ indptr, const int* __restrict__ col,
    unsigned short* __restrict__ agg, int n_nodes) {
    int t = threadIdx.x;
    int node = blockIdx.x * 4 + (t >> 6);
    if (node >= n_nodes) return;
    int lane = t & 63;
    int eg = lane >> 4, fi = lane & 15;
    int e0 = indptr[node], e1 = indptr[node + 1];

    float acc[8] = {0.f, 0.f, 0.f, 0.f, 0.f, 0.f, 0.f, 0.f};
    int elast = (e1 > e0) ? (e1 - 1) : e0;
    for (int base = e0; base < e1; base += 8) {
        int ea = base + eg;
        int eb = base + 4 + eg;
        float sa = (ea < e1) ? 1.f : 0.f;
        float sb = (eb < e1) ? 1.f : 0.f;
        int ca = col[ea < elast ? ea : elast];
        int cb = col[eb < elast ? eb : elast];
        uint4 ua = *(const uint4*)(xsp + (size_t)ca * IN_FEATS + fi * 8);
        uint4 ub = *(const uint4*)(xsp + (size_t)cb * IN_FEATS + fi * 8);
        unsigned pa[4] = {ua.x, ua.y, ua.z, ua.w};
        unsigned pb[4] = {ub.x, ub.y, ub.z, ub.w};
#pragma unroll
        for (int i = 0; i < 4; ++i) {
            acc[2 * i]     = fmaf(sa, __uint_as_float(pa[i] << 16), acc[2 * i]);
            acc[2 * i + 1] = fmaf(sa, __uint_as_float(pa[i] & 0xFFFF0000u), acc[2 * i + 1]);
            acc[2 * i]     = fmaf(sb, __uint_as_float(pb[i] << 16), acc[2 * i]);
            acc[2 * i + 1] = fmaf(sb, __uint_as_float(pb[i] & 0xFFFF0000u), acc[2 * i + 1]);
        }
    }
    // reduce across the 4 edge subgroups (stride 16, 32)
#pragma unroll
    for (int i = 0; i < 8; ++i) {
        acc[i] += __shfl_down(acc[i], 16, 64);
        acc[i] += __shfl_down(acc[i], 32, 64);
    }
    if (eg == 0) {
        int cnt = e1 - e0;
        float inv = 1.0f / (float)(cnt > 0 ? cnt : 1);  // == 1/max(deg,1)
        unsigned o[4];
#pragma unroll
        for (int i = 0; i < 4; ++i) {
            unsigned lo = f2bf(acc[2 * i] * inv);
            unsigned hi = f2bf(acc[2 * i + 1] * inv);
            o[i] = lo | (hi << 16);
        }
        *(uint4*)(agg + (size_t)node * IN_FEATS + fi * 8) = *(uint4*)&o[0];
    }
}

// K3: rst = [agg | feat_bf16] @ Wcat + bias.  M=n_nodes, K=256, N=256.
// 128x128 tile, 4 waves, each wave a 4x4 grid of 16x16x32 bf16 MFMAs.
__global__ __launch_bounds__(256) void k_gemm(
    const unsigned short* __restrict__ agg,   // [N,128] bf16
    const float* __restrict__ feat,           // [N,128] f32 (cast during staging)
    const unsigned short* __restrict__ WT,    // [256][256] bf16, WT[n][k]
    const float* __restrict__ bias,
    float* __restrict__ out, int n_nodes) {
    __shared__ __align__(16) unsigned short Ash[BM * AL];
    __shared__ __align__(16) unsigned short Bsh[BN * AL];
    int t = threadIdx.x;
    int m0 = blockIdx.x * BM;
    int n0 = blockIdx.y * BN;
    int lane = t & 63;
    int w = t >> 6;
    int wr = w >> 1, wc = w & 1;
    int lrow = lane & 15, quad = lane >> 4;

    f32x4 acc[4][4];
    for (int i = 0; i < 4; ++i)
        for (int j = 0; j < 4; ++j)
            acc[i][j] = (f32x4){0.f, 0.f, 0.f, 0.f};

    for (int kk = 0; kk < KTOT; kk += BK) {
        // ---- stage A (128 rows x 32 k, bf16) and B (128 ncols x 32 k) ----
        for (int pass = 0; pass < 2; ++pass) {
            int g = t + pass * 256;          // 0..511 -> (row, 8-elem group)
            int rowi = g >> 2;
            int q = g & 3;
            int gk = kk + q * 8;
            int node = m0 + rowi;
            if (node >= n_nodes) node = n_nodes - 1;  // clamp: keep loads in-bounds
            uint4 v;
            if (kk < IN_FEATS) {
                v = *(const uint4*)(agg + (size_t)node * IN_FEATS + gk);
            } else {
                const float* fp = feat + (size_t)node * IN_FEATS + (gk - IN_FEATS);
                float4 f0 = *(const float4*)fp;
                float4 f1 = *(const float4*)(fp + 4);
                v.x = (unsigned)f2bf(f0.x) | ((unsigned)f2bf(f0.y) << 16);
                v.y = (unsigned)f2bf(f0.z) | ((unsigned)f2bf(f0.w) << 16);
                v.z = (unsigned)f2bf(f1.x) | ((unsigned)f2bf(f1.y) << 16);
                v.w = (unsigned)f2bf(f1.z) | ((unsigned)f2bf(f1.w) << 16);
            }
            *(uint4*)&Ash[rowi * AL + q * 8] = v;

            uint4 bv = *(const uint4*)(WT + (size_t)(n0 + rowi) * KTOT + gk);
            *(uint4*)&Bsh[rowi * AL + q * 8] = bv;
        }
        __syncthreads();

        bf16x8 af[4], bfr[4];
        for (int mi = 0; mi < 4; ++mi)
            af[mi] = *(const bf16x8*)&Ash[(wr * 64 + mi * 16 + lrow) * AL + quad * 8];
        for (int ni = 0; ni < 4; ++ni)
            bfr[ni] = *(const bf16x8*)&Bsh[(wc * 64 + ni * 16 + lrow) * AL + quad * 8];
        for (int mi = 0; mi < 4; ++mi)
            for (int ni = 0; ni < 4; ++ni)
                acc[mi][ni] = __builtin_amdgcn_mfma_f32_16x16x32_bf16(
                    af[mi], bfr[ni], acc[mi][ni], 0, 0, 0);
        __syncthreads();
    }

    // epilogue: C/D layout col=lane&15, row=quad*4+reg
    for (int mi = 0; mi < 4; ++mi) {
        int gm = m0 + wr * 64 + mi * 16 + quad * 4;
        for (int ni = 0; ni < 4; ++ni) {
            int go = n0 + wc * 64 + ni * 16 + lrow;
            float b = bias[go];
            for (int r = 0; r < 4; ++r) {
                int node = gm + r;
                if (node < n_nodes)
                    out[(size_t)node * OUT_FEATS + go] = acc[mi][ni][r] + b;
            }
        }
    }
}

extern "C" void kernel_launch(void* const* d_in, const int* in_sizes, int n_in,
                              void* d_out, int out_size, void* d_ws, size_t ws_size,
                              hipStream_t stream) {
    const float* feat = (const float*)d_in[0];
    const float* tkv  = (const float*)d_in[1];
    const int*   tki  = (const int*)d_in[2];
    const int*   row  = (const int*)d_in[3];
    const int*   col  = (const int*)d_in[4];
    const float* Wn   = (const float*)d_in[6];
    const float* Ws   = (const float*)d_in[7];
    const float* bias = (const float*)d_in[8];
    float* out = (float*)d_out;

    int n_nodes = in_sizes[5];
    int n_edges = in_sizes[3];

    // ws layout: x_sparse bf16 [N,128] | agg bf16 [N,128] | WT bf16 [256,256] | indptr [N+1]
    unsigned short* xsp = (unsigned short*)d_ws;
    unsigned short* agg = xsp + (size_t)n_nodes * IN_FEATS;
    unsigned short* WT  = agg + (size_t)n_nodes * IN_FEATS;
    int* indptr = (int*)(WT + (size_t)OUT_FEATS * KTOT);

    k_scatter<<<(n_nodes + 1) / 2, 256, 0, stream>>>(tkv, tki, xsp, n_nodes);
    k_weights<<<256, 256, 0, stream>>>(Wn, Ws, WT);
    k_indptr<<<(n_edges + 255) / 256, 256, 0, stream>>>(row, indptr, n_nodes, n_edges);
    k_aggregate<<<(n_nodes + 3) / 4, 256, 0, stream>>>(xsp, indptr, col, agg, n_nodes);
    dim3 g3((n_nodes + BM - 1) / BM, OUT_FEATS / BN);
    k_gemm<<<g3, 256, 0, stream>>>(agg, feat, WT, bias, out, n_nodes);
}